// Round 14
// baseline (608.543 us; speedup 1.0000x reference)
//
#include <hip/hip_runtime.h>
#include <hip/hip_bf16.h>

// T=16, N=4, Cin=hidden=64, C4=256, H=W=64
typedef float        f32x4  __attribute__((ext_vector_type(4)));
typedef unsigned int u32x4  __attribute__((ext_vector_type(4)));
typedef __bf16       bf16x8 __attribute__((ext_vector_type(8)));

__device__ __forceinline__ unsigned short f2bf(float f) {
    unsigned u = __builtin_bit_cast(unsigned, f);
    u += 0x7fffu + ((u >> 16) & 1u);          // RTN-even (finite inputs)
    return (unsigned short)(u >> 16);
}
__device__ __forceinline__ float bf2f(unsigned short u) {
    union { unsigned ui; float f; } c; c.ui = ((unsigned)u) << 16; return c.f;
}
// async global->LDS, 16B per lane (dest must be uniform base + lane*16)
__device__ __forceinline__ void gload_lds16(const void* g, void* l) {
    __builtin_amdgcn_global_load_lds(
        (const __attribute__((address_space(1))) unsigned int*)g,
        (__attribute__((address_space(3))) unsigned int*)l, 16, 0, 0);
}

// ---------------------------------------------------------------------------
// xT: [img][pix][ci] bf16  <-  x [img][ci][pix] f32, LDS-transposed so both
// global reads and writes are per-instruction coalesced.
// ---------------------------------------------------------------------------
__global__ __launch_bounds__(256) void k_xT(const float* __restrict__ x,
                                            unsigned short* __restrict__ xT) {
    __shared__ unsigned int tl[256 * 32];     // [pix_local][32 u32], 32 KB
    const int img = blockIdx.x >> 4;
    const int p0  = (blockIdx.x & 15) * 256;
    const int tid = threadIdx.x;
    const float* xi = x + (size_t)img * 64 * 4096 + p0 + tid;
#pragma unroll
    for (int cp = 0; cp < 32; ++cp) {
        float a = xi[(size_t)(2 * cp) * 4096];
        float b = xi[(size_t)(2 * cp + 1) * 4096];
        unsigned v = (unsigned)f2bf(a) | ((unsigned)f2bf(b) << 16);
        tl[tid * 32 + (cp ^ (tid & 31))] = v;        // swizzle: conflict-free
    }
    __syncthreads();
    unsigned short* dst = xT + ((size_t)img * 4096 + p0) * 64;
#pragma unroll
    for (int k = 0; k < 8; ++k) {
        int c = tid + k * 256;                 // 16B-chunk id 0..2047
        int pix = c >> 3, slot = c & 7;
        unsigned w[4];
#pragma unroll
        for (int i = 0; i < 4; ++i)
            w[i] = tl[pix * 32 + ((slot * 4 + i) ^ (pix & 31))];
        *(u32x4*)(dst + (size_t)pix * 64 + slot * 8) = *(u32x4*)w;
    }
}

// ---------------------------------------------------------------------------
// Pack weights [256][64][3][3] f32 -> A bf16 [row][kb][tap][4 slots of 16B]
// (kb-major K order: ks' = kb*9+tap, slab byte offset = ks'*64 within row).
// Chunk pre-swizzle (r4-verified): stored slot s holds source chunk s^(row&3).
// row = hc*4 + g  <->  orig co = g*64 + hc  (gate-interleaved).
// ---------------------------------------------------------------------------
__global__ __launch_bounds__(256) void k_pack(const float* __restrict__ W,
                                              unsigned short* __restrict__ Ap) {
    int idx = blockIdx.x * 256 + threadIdx.x;      // 576 blocks
    if (idx >= 256 * 576) return;
    int row = idx / 576, k = idx % 576;
    int kb = k / 288, r2 = k % 288;
    int tap = r2 / 32, w32 = r2 % 32;
    int s = w32 >> 3, e = w32 & 7;
    int ci = kb * 32 + ((s ^ (row & 3)) << 3) + e;     // pre-swizzle chunks
    int co = (row & 3) * 64 + (row >> 2);              // gate permutation
    Ap[idx] = f2bf(W[((size_t)co * 64 + ci) * 9 + tap]);
}

// ---------------------------------------------------------------------------
// x2h conv: kb-halved halo (20.7 KB, 64B/pos, slot-XOR + pos-parity spread,
// <=2-way banks) -> LDS 28.9 KB -> 5 blocks/CU.  A via global_load_lds dbuf.
// XCD-aware decode, gate-interleaved y, fused BN partials.  grid 4096.
// ---------------------------------------------------------------------------
__global__ __launch_bounds__(256, 5) void k_conv0(
    const unsigned short* __restrict__ src,   // xT [img][4096][64] bf16
    const unsigned short* __restrict__ Ap,    // packed Wx (kb-major)
    unsigned short* __restrict__ ybf,         // y out [img][pix][256r]
    float2* __restrict__ prt)                 // [256r][1024] BN partials
{
    constexpr int TH = 16, N_ = 4, HR = 18;

    __shared__ __align__(16) unsigned short halo[HR * 18 * 32]; // 20736 B
    __shared__ __align__(16) unsigned short As[2][2048];        //  8192 B

    const int bid  = blockIdx.x;
    const int xcd  = bid & 7;
    const int sidx = bid >> 3;
    const int grp  = sidx & 3;
    const int pairG = (sidx >> 2) * 8 + xcd;  // 0..1023
    const int tile = pairG & 15;
    const int img  = pairG >> 4;
    const int py0 = (tile >> 2) * TH, px0 = (tile & 3) * 16;
    const int tid = threadIdx.x;
    const int wv = tid >> 6, lane = tid & 63;
    const int cl = lane & 15, q = lane >> 4;
    const int rowbase = grp * 64;

    f32x4 acc[4][N_];
#pragma unroll
    for (int m = 0; m < 4; ++m)
#pragma unroll
        for (int n = 0; n < N_; ++n)
            acc[m][n] = (f32x4){0.f, 0.f, 0.f, 0.f};

    {
        const unsigned short* sb = src + (size_t)img * 4096 * 64;
        char* hB = (char*)halo;
        auto stage_halo = [&](int kb) {
            for (int tau = tid; tau < HR * 18 * 4; tau += 256) {
                int s = tau & 3, pos = tau >> 2;
                int hcc = pos % 18, hrr = pos / 18;
                int gy = py0 + hrr - 1, gx = px0 + hcc - 1;
                u32x4 v = {0u, 0u, 0u, 0u};
                if ((unsigned)gy < 64u && (unsigned)gx < 64u)
                    v = *(const u32x4*)(sb + ((gy * 64 + gx) * 64 + kb * 32 + s * 8));
                *(u32x4*)(hB + pos * 64 + ((s ^ (hcc & 3)) << 4)) = v;
            }
        };

        const char* agp = (const char*)Ap +
            (size_t)(rowbase + (tid >> 2)) * 1152 + (tid & 3) * 16;
        gload_lds16(agp, (char*)&As[0][0] + tid * 16);     // ks' = 0
        stage_halo(0);
        __syncthreads();

        int aoff[4];
#pragma unroll
        for (int m = 0; m < 4; ++m)
            aoff[m] = (m * 16 + cl) * 64 + ((q * 16) ^ ((cl & 3) << 4));

        const char* AsRd = (const char*)&As[0][0];
#pragma unroll
        for (int ks = 0; ks < 18; ++ks) {                  // ks' = kb*9+tap
            const int buf = ks & 1;
            if (ks < 17)
                gload_lds16(agp + (ks + 1) * 64, (char*)&As[buf ^ 1][0] + tid * 16);

            const int tap = ks % 9;
            const int ky = tap / 3, kx = tap - ky * 3;

            u32x4 af[4];
#pragma unroll
            for (int m = 0; m < 4; ++m)
                af[m] = *(const u32x4*)(AsRd + buf * 4096 + aoff[m]);

            int hcv  = cl + kx;
            int poff = (q ^ (hcv & 3)) << 4;
#pragma unroll
            for (int n = 0; n < N_; ++n) {
                int pos = (wv * N_ + n + ky) * 18 + hcv;
                u32x4 bv = *(const u32x4*)(hB + pos * 64 + poff);
                bf16x8 bfr = __builtin_bit_cast(bf16x8, bv);
#pragma unroll
                for (int m = 0; m < 4; ++m)
                    acc[m][n] = __builtin_amdgcn_mfma_f32_16x16x32_bf16(
                        __builtin_bit_cast(bf16x8, af[m]), bfr, acc[m][n], 0, 0, 0);
            }
            if (ks == 8) {               // end of kb0 taps
                __syncthreads();         // all waves done reading kb0 halo
                stage_halo(1);
            }
            __syncthreads();             // As dbuf swap / halo(1) visible
        }
    }

    // ---- y[img][pix][r]: 8B packed store per (m,n) ----
#pragma unroll
    for (int m = 0; m < 4; ++m) {
#pragma unroll
        for (int n = 0; n < N_; ++n) {
            int pix = (py0 + wv * N_ + n) * 64 + px0 + cl;
            uint2 w;
            w.x = (unsigned)f2bf(acc[m][n][0]) | ((unsigned)f2bf(acc[m][n][1]) << 16);
            w.y = (unsigned)f2bf(acc[m][n][2]) | ((unsigned)f2bf(acc[m][n][3]) << 16);
            *(uint2*)(ybf + ((size_t)img * 4096 + pix) * 256 + rowbase + m * 16 + q * 4) = w;
        }
    }
    // ---- fused BN partial stats: per-block 64-channel (sum, sumsq) ----
    float* bnred = (float*)halo;         // 512 B reuse (k-loop reads done)
#pragma unroll
    for (int m = 0; m < 4; ++m) {
#pragma unroll
        for (int j = 0; j < 4; ++j) {
            float s = 0.f, qq = 0.f;
#pragma unroll
            for (int n = 0; n < N_; ++n) {
                float v = acc[m][n][j];
                s += v; qq += v * v;
            }
#pragma unroll
            for (int mask = 1; mask <= 8; mask <<= 1) {
                s  += __shfl_xor(s,  mask, 64);
                qq += __shfl_xor(qq, mask, 64);
            }
            if (cl == 0) {
                int ci_ = (wv * 4 + q) * 16 + m * 4 + j;
                bnred[ci_ * 2]     = s;
                bnred[ci_ * 2 + 1] = qq;
            }
        }
    }
    __syncthreads();
    if (tid < 64) {
        int m_ = tid >> 4, qj = tid & 15;      // local ch = m*16 + q*4 + j
        float s = 0.f, qq = 0.f;
#pragma unroll
        for (int w = 0; w < 4; ++w) {
            int idx = ((w * 4 + (qj >> 2)) * 16 + m_ * 4 + (qj & 3)) * 2;
            s += bnred[idx]; qq += bnred[idx + 1];
        }
        prt[(size_t)(rowbase + tid) * 1024 + img * 16 + tile] = make_float2(s, qq);
    }
}

// ---------------------------------------------------------------------------
// BN finalize: reduce 1024 per-block partials per channel r -> scale/shift.
// r = hc*4+g  ->  orig co = (r&3)*64 + (r>>2) for gamma/beta lookup.
// ---------------------------------------------------------------------------
__global__ __launch_bounds__(256) void k_bn_fin(
    const float2* __restrict__ prt, const float* __restrict__ bx,
    const float* __restrict__ gamma, const float* __restrict__ beta,
    float* __restrict__ ss) {
    int c = blockIdx.x;                       // 256 blocks (r-index)
    const float2* p = prt + (size_t)c * 1024;
    float s = 0.f, sq = 0.f;
    for (int i = threadIdx.x; i < 1024; i += 256) {
        float2 v = p[i]; s += v.x; sq += v.y;
    }
    __shared__ float rs[256], rq[256];
    int tid = threadIdx.x;
    rs[tid] = s; rq[tid] = sq;
    __syncthreads();
    for (int off = 128; off > 0; off >>= 1) {
        if (tid < off) { rs[tid] += rs[tid + off]; rq[tid] += rq[tid + off]; }
        __syncthreads();
    }
    if (tid == 0) {
        int co = (c & 3) * 64 + (c >> 2);
        float mean = rs[0] * (1.f / 262144.f);
        float var  = rq[0] * (1.f / 262144.f) - mean * mean;
        float sc   = gamma[co] * rsqrtf(var + 1e-5f);
        ss[c]       = sc;
        // conv bias bx cancels exactly in train-mode BN (mean contains it);
        // y was stored WITHOUT bias, so stats already match the bias-free conv:
        ss[256 + c] = beta[co] - mean * sc;
        (void)bx;
    }
}

// ---------------------------------------------------------------------------
// LSTM step (r13 structure: TH=8, N_=2, grid 512, full 8-slot halo).
// kb-major K decode to match the new A pack.  y+c register prefetch;
// t=0 gates c to 0 (no cs memset needed).
// ---------------------------------------------------------------------------
__global__ __launch_bounds__(256) void k_step(
    const unsigned short* __restrict__ hin,   // h [4][4096][64] bf16 (t>0)
    const unsigned short* __restrict__ Ap,    // packed Wh (kb-major)
    const unsigned short* __restrict__ ybf,   // y [img64][pix][256r]
    const float* __restrict__ ss,             // [2][256] scale/shift
    float* __restrict__ cst,                  // c [4][64][4096] f32
    unsigned short* __restrict__ hout,        // h next [4][4096][64]
    float* __restrict__ out,                  // [16][4][64][4096]
    int t, int first)
{
    constexpr int TH = 8, N_ = 2, HR = 10;

    __shared__ __align__(16) unsigned short halo[HR * 18 * 64]; // 23040 B
    __shared__ __align__(16) unsigned short As[2][2048];        //  8192 B

    const int bid  = blockIdx.x;
    const int xcd  = bid & 7;
    const int sidx = bid >> 3;
    const int grp  = sidx & 3;
    const int pairG = (sidx >> 2) * 8 + xcd;  // 0..127
    const int tile = pairG & 31;
    const int img  = pairG >> 5;
    const int py0 = (tile >> 2) * TH, px0 = (tile & 3) * 16;
    const int tid = threadIdx.x;
    const int wv = tid >> 6, lane = tid & 63;
    const int cl = lane & 15, q = lane >> 4;
    const int rowbase = grp * 64;

    // ---- y + c prefetch (HBM latency hidden under k-loop) ----
    uint2 ypre[4][N_];
    float cpre[4][N_];
#pragma unroll
    for (int m = 0; m < 4; ++m) {
        int hc = grp * 16 + m * 4 + q;
#pragma unroll
        for (int n = 0; n < N_; ++n) {
            int pix = (py0 + wv * N_ + n) * 64 + px0 + cl;
            ypre[m][n] = *(const uint2*)(ybf +
                ((size_t)(t * 4 + img) * 4096 + pix) * 256 + hc * 4);
            cpre[m][n] = first ? 0.f : cst[((size_t)img * 64 + hc) * 4096 + pix];
        }
    }

    f32x4 acc[4][N_];
#pragma unroll
    for (int m = 0; m < 4; ++m)
#pragma unroll
        for (int n = 0; n < N_; ++n)
            acc[m][n] = (f32x4){0.f, 0.f, 0.f, 0.f};

    if (!first) {
        const char* agp = (const char*)Ap +
            (size_t)(rowbase + (tid >> 2)) * 1152 + (tid & 3) * 16;
        gload_lds16(agp, (char*)&As[0][0] + tid * 16);     // ks' = 0

        const unsigned short* sb = hin + (size_t)img * 4096 * 64;
        char* hB = (char*)halo;
        for (int tau = tid; tau < HR * 144; tau += 256) {
            int s = tau & 7, hcc = (tau >> 3) % 18, hrr = tau / 144;
            int gy = py0 + hrr - 1, gx = px0 + hcc - 1;
            u32x4 v = {0u, 0u, 0u, 0u};
            if ((unsigned)gy < 64u && (unsigned)gx < 64u)
                v = *(const u32x4*)(sb + ((gy * 64 + gx) * 64 + s * 8));
            *(u32x4*)(hB + (hrr * 18 + hcc) * 128 + ((s * 16) ^ ((hcc & 7) << 4))) = v;
        }
        __syncthreads();

        int aoff[4];
#pragma unroll
        for (int m = 0; m < 4; ++m)
            aoff[m] = (m * 16 + cl) * 64 + ((q * 16) ^ ((cl & 3) << 4));

        const char* AsRd = (const char*)&As[0][0];
#pragma unroll
        for (int ks = 0; ks < 18; ++ks) {                  // ks' = kb*9+tap
            const int buf = ks & 1;
            if (ks < 17)
                gload_lds16(agp + (ks + 1) * 64, (char*)&As[buf ^ 1][0] + tid * 16);

            const int kb = ks / 9, tap = ks % 9;
            const int ky = tap / 3, kx = tap - ky * 3;

            u32x4 af[4];
#pragma unroll
            for (int m = 0; m < 4; ++m)
                af[m] = *(const u32x4*)(AsRd + buf * 4096 + aoff[m]);

            int hcv  = cl + kx;
            int cbase = hcv * 128 + ((kb * 64 + q * 16) ^ ((hcv & 7) << 4));
#pragma unroll
            for (int n = 0; n < N_; ++n) {
                int hr = wv * N_ + n + ky;
                u32x4 bv = *(const u32x4*)(hB + hr * 2304 + cbase);
                bf16x8 bfr = __builtin_bit_cast(bf16x8, bv);
#pragma unroll
                for (int m = 0; m < 4; ++m)
                    acc[m][n] = __builtin_amdgcn_mfma_f32_16x16x32_bf16(
                        __builtin_bit_cast(bf16x8, af[m]), bfr, acc[m][n], 0, 0, 0);
            }
            __syncthreads();
        }
    }

    // ---- epilogue: gates, c, h ----
    unsigned short* hbounce = halo;          // reuse (k-loop reads done)
    const f32x4* sc4 = (const f32x4*)ss;
    const f32x4* sh4 = (const f32x4*)(ss + 256);
#pragma unroll
    for (int m = 0; m < 4; ++m) {
        int hc = grp * 16 + m * 4 + q;
        f32x4 sc = sc4[hc], sh = sh4[hc];
#pragma unroll
        for (int n = 0; n < N_; ++n) {
            int pix = (py0 + wv * N_ + n) * 64 + px0 + cl;
            uint2 yv = ypre[m][n];
            float tmp[4];
            tmp[0] = acc[m][n][0] + sc[0] * bf2f((unsigned short)(yv.x & 0xffffu)) + sh[0];
            tmp[1] = acc[m][n][1] + sc[1] * bf2f((unsigned short)(yv.x >> 16))     + sh[1];
            tmp[2] = acc[m][n][2] + sc[2] * bf2f((unsigned short)(yv.y & 0xffffu)) + sh[2];
            tmp[3] = acc[m][n][3] + sc[3] * bf2f((unsigned short)(yv.y >> 16))     + sh[3];
            float iv = 1.f / (1.f + __expf(-tmp[0]));
            float fv = 1.f / (1.f + __expf(-tmp[1]));
            float ov = 1.f / (1.f + __expf(-tmp[2]));
            float e2 = __expf(2.f * tmp[3]);
            float gv = 1.f - 2.f / (e2 + 1.f);
            size_t cidx = ((size_t)img * 64 + hc) * 4096 + pix;
            float cnew = fv * cpre[m][n] + iv * gv;
            cst[cidx] = cnew;
            float e2c = __expf(2.f * cnew);
            float hv  = ov * (1.f - 2.f / (e2c + 1.f));
            out[((size_t)(t * 4 + img) * 64 + hc) * 4096 + pix] = hv;
            hbounce[((wv * N_ + n) * 16 + cl) * 16 + m * 4 + q] = f2bf(hv);
        }
    }
    __syncthreads();
    // coalesced hT write-out: [img][pix][ci] slice grp*16..grp*16+15
    if (tid < TH * 16) {
        int pixg = (py0 + (tid >> 4)) * 64 + px0 + (tid & 15);
        u32x4* dst = (u32x4*)(hout + ((size_t)img * 4096 + pixg) * 64 + grp * 16);
        u32x4* s0  = (u32x4*)(hbounce + tid * 16);
        dst[0] = s0[0];
        dst[1] = s0[1];
    }
}

// ---------------------------------------------------------------------------
extern "C" void kernel_launch(void* const* d_in, const int* in_sizes, int n_in,
                              void* d_out, int out_size, void* d_ws, size_t ws_size,
                              hipStream_t stream) {
    const float* x     = (const float*)d_in[0];
    const float* Wx    = (const float*)d_in[1];
    const float* bx    = (const float*)d_in[2];
    const float* gamma = (const float*)d_in[3];
    const float* beta  = (const float*)d_in[4];
    const float* Wh    = (const float*)d_in[5];
    float* out = (float*)d_out;

    char* ws = (char*)d_ws;
    unsigned short* y   = (unsigned short*)ws;                  // 134,217,728
    unsigned short* Axp = (unsigned short*)(ws + 134217728);    //     294,912
    unsigned short* Ahp = (unsigned short*)(ws + 134512640);    //     294,912
    float*          ss  = (float*)(ws + 134807552);             //       2,048
    float*          cs  = (float*)(ws + 134809600);             //   4,194,304
    // prt and hA share a 2 MB slot: prt is produced by k_conv0 and fully
    // consumed by k_bn_fin before k_step first writes hA (at t=1).
    float2*         prt = (float2*)(ws + 139003904);            //   2,097,152
    unsigned short* hA  = (unsigned short*)(ws + 139003904);    //   (alias)
    unsigned short* hB  = (unsigned short*)(ws + 141101056);    //   2,097,152
    // total 143,198,208 B

    // xT scratch lives in d_out (dead once steps start overwriting it)
    unsigned short* xT = (unsigned short*)d_out;

    k_xT  <<<1024, 256, 0, stream>>>(x, xT);
    k_pack<<< 576, 256, 0, stream>>>(Wx, Axp);
    k_pack<<< 576, 256, 0, stream>>>(Wh, Ahp);

    k_conv0<<<4096, 256, 0, stream>>>(xT, Axp, y, prt);
    k_bn_fin<<<256, 256, 0, stream>>>(prt, bx, gamma, beta, ss);

    unsigned short* hbuf[2] = {hA, hB};
    for (int t = 0; t < 16; ++t) {
        k_step<<<512, 256, 0, stream>>>(hbuf[t & 1], Ahp, y, ss, cs,
                                        hbuf[(t + 1) & 1], out, t, t == 0 ? 1 : 0);
    }
}

// Round 15
// 403.850 us; speedup vs baseline: 1.5069x; 1.5069x over previous
//
#include <hip/hip_runtime.h>
#include <hip/hip_bf16.h>

// T=16, N=4, Cin=hidden=64, C4=256, H=W=64
typedef float        f32x4  __attribute__((ext_vector_type(4)));
typedef unsigned int u32x4  __attribute__((ext_vector_type(4)));
typedef __bf16       bf16x8 __attribute__((ext_vector_type(8)));

__device__ __forceinline__ unsigned short f2bf(float f) {
    unsigned u = __builtin_bit_cast(unsigned, f);
    u += 0x7fffu + ((u >> 16) & 1u);          // RTN-even (finite inputs)
    return (unsigned short)(u >> 16);
}
__device__ __forceinline__ float bf2f(unsigned short u) {
    union { unsigned ui; float f; } c; c.ui = ((unsigned)u) << 16; return c.f;
}
// async global->LDS, 16B per lane (dest must be uniform base + lane*16)
__device__ __forceinline__ void gload_lds16(const void* g, void* l) {
    __builtin_amdgcn_global_load_lds(
        (const __attribute__((address_space(1))) unsigned int*)g,
        (__attribute__((address_space(3))) unsigned int*)l, 16, 0, 0);
}

// ---------------------------------------------------------------------------
// xT: [img][pix][ci] bf16  <-  x [img][ci][pix] f32, LDS-transposed so both
// global reads and writes are per-instruction coalesced.
// ---------------------------------------------------------------------------
__global__ __launch_bounds__(256) void k_xT(const float* __restrict__ x,
                                            unsigned short* __restrict__ xT) {
    __shared__ unsigned int tl[256 * 32];     // [pix_local][32 u32], 32 KB
    const int img = blockIdx.x >> 4;
    const int p0  = (blockIdx.x & 15) * 256;
    const int tid = threadIdx.x;
    const float* xi = x + (size_t)img * 64 * 4096 + p0 + tid;
#pragma unroll
    for (int cp = 0; cp < 32; ++cp) {
        float a = xi[(size_t)(2 * cp) * 4096];
        float b = xi[(size_t)(2 * cp + 1) * 4096];
        unsigned v = (unsigned)f2bf(a) | ((unsigned)f2bf(b) << 16);
        tl[tid * 32 + (cp ^ (tid & 31))] = v;        // swizzle: conflict-free
    }
    __syncthreads();
    unsigned short* dst = xT + ((size_t)img * 4096 + p0) * 64;
#pragma unroll
    for (int k = 0; k < 8; ++k) {
        int c = tid + k * 256;                 // 16B-chunk id 0..2047
        int pix = c >> 3, slot = c & 7;
        unsigned w[4];
#pragma unroll
        for (int i = 0; i < 4; ++i)
            w[i] = tl[pix * 32 + ((slot * 4 + i) ^ (pix & 31))];
        *(u32x4*)(dst + (size_t)pix * 64 + slot * 8) = *(u32x4*)w;
    }
}

// ---------------------------------------------------------------------------
// Pack weights [256][64][3][3] f32 -> A bf16 [row][kb][tap][4 slots of 16B]
// (kb-major K order: ks' = kb*9+tap, slab byte offset = ks'*64 within row).
// Chunk pre-swizzle (r4-verified): stored slot s holds source chunk s^(row&3).
// row = hc*4 + g  <->  orig co = g*64 + hc  (gate-interleaved).
// ---------------------------------------------------------------------------
__global__ __launch_bounds__(256) void k_pack(const float* __restrict__ W,
                                              unsigned short* __restrict__ Ap) {
    int idx = blockIdx.x * 256 + threadIdx.x;      // 576 blocks
    if (idx >= 256 * 576) return;
    int row = idx / 576, k = idx % 576;
    int kb = k / 288, r2 = k % 288;
    int tap = r2 / 32, w32 = r2 % 32;
    int s = w32 >> 3, e = w32 & 7;
    int ci = kb * 32 + ((s ^ (row & 3)) << 3) + e;     // pre-swizzle chunks
    int co = (row & 3) * 64 + (row >> 2);              // gate permutation
    Ap[idx] = f2bf(W[((size_t)co * 64 + ci) * 9 + tap]);
}

// ---------------------------------------------------------------------------
// x2h conv: kb-halved halo (20.7 KB, 64B/pos, slot-XOR, <=2-way banks)
// -> LDS 28.9 KB.  NO min-waves clamp (r14's ,5 caused a 1.38 GB spill).
// A via global_load_lds dbuf.  XCD decode, gate-interleaved y, fused BN.
// grid 4096 = 64img*16tile*4cog.
// ---------------------------------------------------------------------------
__global__ __launch_bounds__(256) void k_conv0(
    const unsigned short* __restrict__ src,   // xT [img][4096][64] bf16
    const unsigned short* __restrict__ Ap,    // packed Wx (kb-major)
    unsigned short* __restrict__ ybf,         // y out [img][pix][256r]
    float2* __restrict__ prt)                 // [256r][1024] BN partials
{
    constexpr int TH = 16, N_ = 4, HR = 18;

    __shared__ __align__(16) unsigned short halo[HR * 18 * 32]; // 20736 B
    __shared__ __align__(16) unsigned short As[2][2048];        //  8192 B

    const int bid  = blockIdx.x;
    const int xcd  = bid & 7;
    const int sidx = bid >> 3;
    const int grp  = sidx & 3;
    const int pairG = (sidx >> 2) * 8 + xcd;  // 0..1023
    const int tile = pairG & 15;
    const int img  = pairG >> 4;
    const int py0 = (tile >> 2) * TH, px0 = (tile & 3) * 16;
    const int tid = threadIdx.x;
    const int wv = tid >> 6, lane = tid & 63;
    const int cl = lane & 15, q = lane >> 4;
    const int rowbase = grp * 64;

    f32x4 acc[4][N_];
#pragma unroll
    for (int m = 0; m < 4; ++m)
#pragma unroll
        for (int n = 0; n < N_; ++n)
            acc[m][n] = (f32x4){0.f, 0.f, 0.f, 0.f};

    {
        const unsigned short* sb = src + (size_t)img * 4096 * 64;
        char* hB = (char*)halo;
        auto stage_halo = [&](int kb) {
            for (int tau = tid; tau < HR * 18 * 4; tau += 256) {
                int s = tau & 3, pos = tau >> 2;
                int hcc = pos % 18, hrr = pos / 18;
                int gy = py0 + hrr - 1, gx = px0 + hcc - 1;
                u32x4 v = {0u, 0u, 0u, 0u};
                if ((unsigned)gy < 64u && (unsigned)gx < 64u)
                    v = *(const u32x4*)(sb + ((gy * 64 + gx) * 64 + kb * 32 + s * 8));
                *(u32x4*)(hB + pos * 64 + ((s ^ (hcc & 3)) << 4)) = v;
            }
        };

        const char* agp = (const char*)Ap +
            (size_t)(rowbase + (tid >> 2)) * 1152 + (tid & 3) * 16;
        gload_lds16(agp, (char*)&As[0][0] + tid * 16);     // ks' = 0
        stage_halo(0);
        __syncthreads();

        int aoff[4];
#pragma unroll
        for (int m = 0; m < 4; ++m)
            aoff[m] = (m * 16 + cl) * 64 + ((q * 16) ^ ((cl & 3) << 4));

        const char* AsRd = (const char*)&As[0][0];
#pragma unroll
        for (int ks = 0; ks < 18; ++ks) {                  // ks' = kb*9+tap
            const int buf = ks & 1;
            if (ks < 17)
                gload_lds16(agp + (ks + 1) * 64, (char*)&As[buf ^ 1][0] + tid * 16);

            const int tap = ks % 9;
            const int ky = tap / 3, kx = tap - ky * 3;

            u32x4 af[4];
#pragma unroll
            for (int m = 0; m < 4; ++m)
                af[m] = *(const u32x4*)(AsRd + buf * 4096 + aoff[m]);

            int hcv  = cl + kx;
            int poff = (q ^ (hcv & 3)) << 4;
#pragma unroll
            for (int n = 0; n < N_; ++n) {
                int pos = (wv * N_ + n + ky) * 18 + hcv;
                u32x4 bv = *(const u32x4*)(hB + pos * 64 + poff);
                bf16x8 bfr = __builtin_bit_cast(bf16x8, bv);
#pragma unroll
                for (int m = 0; m < 4; ++m)
                    acc[m][n] = __builtin_amdgcn_mfma_f32_16x16x32_bf16(
                        __builtin_bit_cast(bf16x8, af[m]), bfr, acc[m][n], 0, 0, 0);
            }
            if (ks == 8) {               // end of kb0 taps
                __syncthreads();         // all waves done reading kb0 halo
                stage_halo(1);
            }
            __syncthreads();             // As dbuf swap / halo(1) visible
        }
    }

    // ---- y[img][pix][r]: 8B packed store per (m,n) ----
#pragma unroll
    for (int m = 0; m < 4; ++m) {
#pragma unroll
        for (int n = 0; n < N_; ++n) {
            int pix = (py0 + wv * N_ + n) * 64 + px0 + cl;
            uint2 w;
            w.x = (unsigned)f2bf(acc[m][n][0]) | ((unsigned)f2bf(acc[m][n][1]) << 16);
            w.y = (unsigned)f2bf(acc[m][n][2]) | ((unsigned)f2bf(acc[m][n][3]) << 16);
            *(uint2*)(ybf + ((size_t)img * 4096 + pix) * 256 + rowbase + m * 16 + q * 4) = w;
        }
    }
    // ---- fused BN partial stats: per-block 64-channel (sum, sumsq) ----
    float* bnred = (float*)halo;         // 512 B reuse (k-loop reads done)
#pragma unroll
    for (int m = 0; m < 4; ++m) {
#pragma unroll
        for (int j = 0; j < 4; ++j) {
            float s = 0.f, qq = 0.f;
#pragma unroll
            for (int n = 0; n < N_; ++n) {
                float v = acc[m][n][j];
                s += v; qq += v * v;
            }
#pragma unroll
            for (int mask = 1; mask <= 8; mask <<= 1) {
                s  += __shfl_xor(s,  mask, 64);
                qq += __shfl_xor(qq, mask, 64);
            }
            if (cl == 0) {
                int ci_ = (wv * 4 + q) * 16 + m * 4 + j;
                bnred[ci_ * 2]     = s;
                bnred[ci_ * 2 + 1] = qq;
            }
        }
    }
    __syncthreads();
    if (tid < 64) {
        int m_ = tid >> 4, qj = tid & 15;      // local ch = m*16 + q*4 + j
        float s = 0.f, qq = 0.f;
#pragma unroll
        for (int w = 0; w < 4; ++w) {
            int idx = ((w * 4 + (qj >> 2)) * 16 + m_ * 4 + (qj & 3)) * 2;
            s += bnred[idx]; qq += bnred[idx + 1];
        }
        prt[(size_t)(rowbase + tid) * 1024 + img * 16 + tile] = make_float2(s, qq);
    }
}

// ---------------------------------------------------------------------------
// BN finalize: reduce 1024 per-block partials per channel r -> scale/shift.
// r = hc*4+g  ->  orig co = (r&3)*64 + (r>>2) for gamma/beta lookup.
// ---------------------------------------------------------------------------
__global__ __launch_bounds__(256) void k_bn_fin(
    const float2* __restrict__ prt, const float* __restrict__ bx,
    const float* __restrict__ gamma, const float* __restrict__ beta,
    float* __restrict__ ss) {
    int c = blockIdx.x;                       // 256 blocks (r-index)
    const float2* p = prt + (size_t)c * 1024;
    float s = 0.f, sq = 0.f;
    for (int i = threadIdx.x; i < 1024; i += 256) {
        float2 v = p[i]; s += v.x; sq += v.y;
    }
    __shared__ float rs[256], rq[256];
    int tid = threadIdx.x;
    rs[tid] = s; rq[tid] = sq;
    __syncthreads();
    for (int off = 128; off > 0; off >>= 1) {
        if (tid < off) { rs[tid] += rs[tid + off]; rq[tid] += rq[tid + off]; }
        __syncthreads();
    }
    if (tid == 0) {
        int co = (c & 3) * 64 + (c >> 2);
        float mean = rs[0] * (1.f / 262144.f);
        float var  = rq[0] * (1.f / 262144.f) - mean * mean;
        float sc   = gamma[co] * rsqrtf(var + 1e-5f);
        ss[c]       = sc;
        // conv bias bx cancels exactly in train-mode BN (mean contains it);
        // y was stored WITHOUT bias, so stats already match the bias-free conv:
        ss[256 + c] = beta[co] - mean * sc;
        (void)bx;
    }
}

// ---------------------------------------------------------------------------
// LSTM step (TH=8, N_=2, grid 512, full 8-slot halo).  kb-major K decode.
// y+c register prefetch; t=0 gates c to 0 (no cs memset needed).
// ---------------------------------------------------------------------------
__global__ __launch_bounds__(256) void k_step(
    const unsigned short* __restrict__ hin,   // h [4][4096][64] bf16 (t>0)
    const unsigned short* __restrict__ Ap,    // packed Wh (kb-major)
    const unsigned short* __restrict__ ybf,   // y [img64][pix][256r]
    const float* __restrict__ ss,             // [2][256] scale/shift
    float* __restrict__ cst,                  // c [4][64][4096] f32
    unsigned short* __restrict__ hout,        // h next [4][4096][64]
    float* __restrict__ out,                  // [16][4][64][4096]
    int t, int first)
{
    constexpr int TH = 8, N_ = 2, HR = 10;

    __shared__ __align__(16) unsigned short halo[HR * 18 * 64]; // 23040 B
    __shared__ __align__(16) unsigned short As[2][2048];        //  8192 B

    const int bid  = blockIdx.x;
    const int xcd  = bid & 7;
    const int sidx = bid >> 3;
    const int grp  = sidx & 3;
    const int pairG = (sidx >> 2) * 8 + xcd;  // 0..127
    const int tile = pairG & 31;
    const int img  = pairG >> 5;
    const int py0 = (tile >> 2) * TH, px0 = (tile & 3) * 16;
    const int tid = threadIdx.x;
    const int wv = tid >> 6, lane = tid & 63;
    const int cl = lane & 15, q = lane >> 4;
    const int rowbase = grp * 64;

    // ---- y + c prefetch (HBM latency hidden under k-loop) ----
    uint2 ypre[4][N_];
    float cpre[4][N_];
#pragma unroll
    for (int m = 0; m < 4; ++m) {
        int hc = grp * 16 + m * 4 + q;
#pragma unroll
        for (int n = 0; n < N_; ++n) {
            int pix = (py0 + wv * N_ + n) * 64 + px0 + cl;
            ypre[m][n] = *(const uint2*)(ybf +
                ((size_t)(t * 4 + img) * 4096 + pix) * 256 + hc * 4);
            cpre[m][n] = first ? 0.f : cst[((size_t)img * 64 + hc) * 4096 + pix];
        }
    }

    f32x4 acc[4][N_];
#pragma unroll
    for (int m = 0; m < 4; ++m)
#pragma unroll
        for (int n = 0; n < N_; ++n)
            acc[m][n] = (f32x4){0.f, 0.f, 0.f, 0.f};

    if (!first) {
        const char* agp = (const char*)Ap +
            (size_t)(rowbase + (tid >> 2)) * 1152 + (tid & 3) * 16;
        gload_lds16(agp, (char*)&As[0][0] + tid * 16);     // ks' = 0

        const unsigned short* sb = hin + (size_t)img * 4096 * 64;
        char* hB = (char*)halo;
        for (int tau = tid; tau < HR * 144; tau += 256) {
            int s = tau & 7, hcc = (tau >> 3) % 18, hrr = tau / 144;
            int gy = py0 + hrr - 1, gx = px0 + hcc - 1;
            u32x4 v = {0u, 0u, 0u, 0u};
            if ((unsigned)gy < 64u && (unsigned)gx < 64u)
                v = *(const u32x4*)(sb + ((gy * 64 + gx) * 64 + s * 8));
            *(u32x4*)(hB + (hrr * 18 + hcc) * 128 + ((s * 16) ^ ((hcc & 7) << 4))) = v;
        }
        __syncthreads();

        int aoff[4];
#pragma unroll
        for (int m = 0; m < 4; ++m)
            aoff[m] = (m * 16 + cl) * 64 + ((q * 16) ^ ((cl & 3) << 4));

        const char* AsRd = (const char*)&As[0][0];
#pragma unroll
        for (int ks = 0; ks < 18; ++ks) {                  // ks' = kb*9+tap
            const int buf = ks & 1;
            if (ks < 17)
                gload_lds16(agp + (ks + 1) * 64, (char*)&As[buf ^ 1][0] + tid * 16);

            const int kb = ks / 9, tap = ks % 9;
            const int ky = tap / 3, kx = tap - ky * 3;

            u32x4 af[4];
#pragma unroll
            for (int m = 0; m < 4; ++m)
                af[m] = *(const u32x4*)(AsRd + buf * 4096 + aoff[m]);

            int hcv  = cl + kx;
            int cbase = hcv * 128 + ((kb * 64 + q * 16) ^ ((hcv & 7) << 4));
#pragma unroll
            for (int n = 0; n < N_; ++n) {
                int hr = wv * N_ + n + ky;
                u32x4 bv = *(const u32x4*)(hB + hr * 2304 + cbase);
                bf16x8 bfr = __builtin_bit_cast(bf16x8, bv);
#pragma unroll
                for (int m = 0; m < 4; ++m)
                    acc[m][n] = __builtin_amdgcn_mfma_f32_16x16x32_bf16(
                        __builtin_bit_cast(bf16x8, af[m]), bfr, acc[m][n], 0, 0, 0);
            }
            __syncthreads();
        }
    }

    // ---- epilogue: gates, c, h ----
    unsigned short* hbounce = halo;          // reuse (k-loop reads done)
    const f32x4* sc4 = (const f32x4*)ss;
    const f32x4* sh4 = (const f32x4*)(ss + 256);
#pragma unroll
    for (int m = 0; m < 4; ++m) {
        int hc = grp * 16 + m * 4 + q;
        f32x4 sc = sc4[hc], sh = sh4[hc];
#pragma unroll
        for (int n = 0; n < N_; ++n) {
            int pix = (py0 + wv * N_ + n) * 64 + px0 + cl;
            uint2 yv = ypre[m][n];
            float tmp[4];
            tmp[0] = acc[m][n][0] + sc[0] * bf2f((unsigned short)(yv.x & 0xffffu)) + sh[0];
            tmp[1] = acc[m][n][1] + sc[1] * bf2f((unsigned short)(yv.x >> 16))     + sh[1];
            tmp[2] = acc[m][n][2] + sc[2] * bf2f((unsigned short)(yv.y & 0xffffu)) + sh[2];
            tmp[3] = acc[m][n][3] + sc[3] * bf2f((unsigned short)(yv.y >> 16))     + sh[3];
            float iv = 1.f / (1.f + __expf(-tmp[0]));
            float fv = 1.f / (1.f + __expf(-tmp[1]));
            float ov = 1.f / (1.f + __expf(-tmp[2]));
            float e2 = __expf(2.f * tmp[3]);
            float gv = 1.f - 2.f / (e2 + 1.f);
            size_t cidx = ((size_t)img * 64 + hc) * 4096 + pix;
            float cnew = fv * cpre[m][n] + iv * gv;
            cst[cidx] = cnew;
            float e2c = __expf(2.f * cnew);
            float hv  = ov * (1.f - 2.f / (e2c + 1.f));
            out[((size_t)(t * 4 + img) * 64 + hc) * 4096 + pix] = hv;
            hbounce[((wv * N_ + n) * 16 + cl) * 16 + m * 4 + q] = f2bf(hv);
        }
    }
    __syncthreads();
    // coalesced hT write-out: [img][pix][ci] slice grp*16..grp*16+15
    if (tid < TH * 16) {
        int pixg = (py0 + (tid >> 4)) * 64 + px0 + (tid & 15);
        u32x4* dst = (u32x4*)(hout + ((size_t)img * 4096 + pixg) * 64 + grp * 16);
        u32x4* s0  = (u32x4*)(hbounce + tid * 16);
        dst[0] = s0[0];
        dst[1] = s0[1];
    }
}

// ---------------------------------------------------------------------------
extern "C" void kernel_launch(void* const* d_in, const int* in_sizes, int n_in,
                              void* d_out, int out_size, void* d_ws, size_t ws_size,
                              hipStream_t stream) {
    const float* x     = (const float*)d_in[0];
    const float* Wx    = (const float*)d_in[1];
    const float* bx    = (const float*)d_in[2];
    const float* gamma = (const float*)d_in[3];
    const float* beta  = (const float*)d_in[4];
    const float* Wh    = (const float*)d_in[5];
    float* out = (float*)d_out;

    char* ws = (char*)d_ws;
    unsigned short* y   = (unsigned short*)ws;                  // 134,217,728
    unsigned short* Axp = (unsigned short*)(ws + 134217728);    //     294,912
    unsigned short* Ahp = (unsigned short*)(ws + 134512640);    //     294,912
    float*          ss  = (float*)(ws + 134807552);             //       2,048
    float*          cs  = (float*)(ws + 134809600);             //   4,194,304
    // prt and hA share a 2 MB slot: prt is produced by k_conv0 and fully
    // consumed by k_bn_fin before k_step first writes hA (at t=1).
    float2*         prt = (float2*)(ws + 139003904);            //   2,097,152
    unsigned short* hA  = (unsigned short*)(ws + 139003904);    //   (alias)
    unsigned short* hB  = (unsigned short*)(ws + 141101056);    //   2,097,152
    // total 143,198,208 B

    // xT scratch lives in d_out (dead once steps start overwriting it)
    unsigned short* xT = (unsigned short*)d_out;

    k_xT  <<<1024, 256, 0, stream>>>(x, xT);
    k_pack<<< 576, 256, 0, stream>>>(Wx, Axp);
    k_pack<<< 576, 256, 0, stream>>>(Wh, Ahp);

    k_conv0<<<4096, 256, 0, stream>>>(xT, Axp, y, prt);
    k_bn_fin<<<256, 256, 0, stream>>>(prt, bx, gamma, beta, ss);

    unsigned short* hbuf[2] = {hA, hB};
    for (int t = 0; t < 16; ++t) {
        k_step<<<512, 256, 0, stream>>>(hbuf[t & 1], Ahp, y, ss, cs,
                                        hbuf[(t + 1) & 1], out, t, t == 0 ? 1 : 0);
    }
}

// Round 16
// 382.658 us; speedup vs baseline: 1.5903x; 1.0554x over previous
//
#include <hip/hip_runtime.h>
#include <hip/hip_bf16.h>

// T=16, N=4, Cin=hidden=64, C4=256, H=W=64
typedef float        f32x4  __attribute__((ext_vector_type(4)));
typedef unsigned int u32x4  __attribute__((ext_vector_type(4)));
typedef __bf16       bf16x8 __attribute__((ext_vector_type(8)));

__device__ __forceinline__ unsigned short f2bf(float f) {
    unsigned u = __builtin_bit_cast(unsigned, f);
    u += 0x7fffu + ((u >> 16) & 1u);          // RTN-even (finite inputs)
    return (unsigned short)(u >> 16);
}
__device__ __forceinline__ float bf2f(unsigned short u) {
    union { unsigned ui; float f; } c; c.ui = ((unsigned)u) << 16; return c.f;
}
// async global->LDS, 16B per lane (dest must be uniform base + lane*16)
__device__ __forceinline__ void gload_lds16(const void* g, void* l) {
    __builtin_amdgcn_global_load_lds(
        (const __attribute__((address_space(1))) unsigned int*)g,
        (__attribute__((address_space(3))) unsigned int*)l, 16, 0, 0);
}

// ---------------------------------------------------------------------------
// xT: [img][pix][ci] bf16  <-  x [img][ci][pix] f32, LDS-transposed so both
// global reads and writes are per-instruction coalesced (r15-verified).
// ---------------------------------------------------------------------------
__global__ __launch_bounds__(256) void k_xT(const float* __restrict__ x,
                                            unsigned short* __restrict__ xT) {
    __shared__ unsigned int tl[256 * 32];     // [pix_local][32 u32], 32 KB
    const int img = blockIdx.x >> 4;
    const int p0  = (blockIdx.x & 15) * 256;
    const int tid = threadIdx.x;
    const float* xi = x + (size_t)img * 64 * 4096 + p0 + tid;
#pragma unroll
    for (int cp = 0; cp < 32; ++cp) {
        float a = xi[(size_t)(2 * cp) * 4096];
        float b = xi[(size_t)(2 * cp + 1) * 4096];
        unsigned v = (unsigned)f2bf(a) | ((unsigned)f2bf(b) << 16);
        tl[tid * 32 + (cp ^ (tid & 31))] = v;        // swizzle: conflict-free
    }
    __syncthreads();
    unsigned short* dst = xT + ((size_t)img * 4096 + p0) * 64;
#pragma unroll
    for (int k = 0; k < 8; ++k) {
        int c = tid + k * 256;                 // 16B-chunk id 0..2047
        int pix = c >> 3, slot = c & 7;
        unsigned w[4];
#pragma unroll
        for (int i = 0; i < 4; ++i)
            w[i] = tl[pix * 32 + ((slot * 4 + i) ^ (pix & 31))];
        *(u32x4*)(dst + (size_t)pix * 64 + slot * 8) = *(u32x4*)w;
    }
}

// ---------------------------------------------------------------------------
// Pack weights [256][64][3][3] f32 -> A bf16 [row][kb][tap][4 slots of 16B]
// (kb-major K order: ks' = kb*9+tap, slab byte offset = ks'*64 within row).
// Chunk pre-swizzle (r4-verified): stored slot s holds source chunk s^(row&3).
// row = hc*4 + g  <->  orig co = g*64 + hc  (gate-interleaved).
// ---------------------------------------------------------------------------
__global__ __launch_bounds__(256) void k_pack(const float* __restrict__ W,
                                              unsigned short* __restrict__ Ap) {
    int idx = blockIdx.x * 256 + threadIdx.x;      // 576 blocks
    if (idx >= 256 * 576) return;
    int row = idx / 576, k = idx % 576;
    int kb = k / 288, r2 = k % 288;
    int tap = r2 / 32, w32 = r2 % 32;
    int s = w32 >> 3, e = w32 & 7;
    int ci = kb * 32 + ((s ^ (row & 3)) << 3) + e;     // pre-swizzle chunks
    int co = (row & 3) * 64 + (row >> 2);              // gate permutation
    Ap[idx] = f2bf(W[((size_t)co * 64 + ci) * 9 + tap]);
}

// ---------------------------------------------------------------------------
// x2h conv (r13-verified structure): full 128B-XOR halo (the ONLY layout
// measured conflict-clean), global_load_lds A dbuf, unrolled 18-ks loop with
// kb-major decode.  XCD decode, gate-interleaved y, fused BN partials.
// grid 4096 = 64img*16tile*4cog.
// ---------------------------------------------------------------------------
__global__ __launch_bounds__(256) void k_conv0(
    const unsigned short* __restrict__ src,   // xT [img][4096][64] bf16
    const unsigned short* __restrict__ Ap,    // packed Wx (kb-major)
    unsigned short* __restrict__ ybf,         // y out [img][pix][256r]
    float2* __restrict__ prt)                 // [256r][1024] BN partials
{
    constexpr int TH = 16, N_ = 4, HR = 18;

    __shared__ __align__(16) unsigned short halo[HR * 18 * 64]; // 41472 B
    __shared__ __align__(16) unsigned short As[2][2048];        //  8192 B

    const int bid  = blockIdx.x;
    const int xcd  = bid & 7;
    const int sidx = bid >> 3;
    const int grp  = sidx & 3;
    const int pairG = (sidx >> 2) * 8 + xcd;  // 0..1023
    const int tile = pairG & 15;
    const int img  = pairG >> 4;
    const int py0 = (tile >> 2) * TH, px0 = (tile & 3) * 16;
    const int tid = threadIdx.x;
    const int wv = tid >> 6, lane = tid & 63;
    const int cl = lane & 15, q = lane >> 4;
    const int rowbase = grp * 64;

    f32x4 acc[4][N_];
#pragma unroll
    for (int m = 0; m < 4; ++m)
#pragma unroll
        for (int n = 0; n < N_; ++n)
            acc[m][n] = (f32x4){0.f, 0.f, 0.f, 0.f};

    {
        const char* agp = (const char*)Ap +
            (size_t)(rowbase + (tid >> 2)) * 1152 + (tid & 3) * 16;
        gload_lds16(agp, (char*)&As[0][0] + tid * 16);     // ks' = 0

        const unsigned short* sb = src + (size_t)img * 4096 * 64;
        char* hB = (char*)halo;
        for (int tau = tid; tau < HR * 144; tau += 256) {
            int s = tau & 7, hcc = (tau >> 3) % 18, hrr = tau / 144;
            int gy = py0 + hrr - 1, gx = px0 + hcc - 1;
            u32x4 v = {0u, 0u, 0u, 0u};
            if ((unsigned)gy < 64u && (unsigned)gx < 64u)
                v = *(const u32x4*)(sb + ((gy * 64 + gx) * 64 + s * 8));
            *(u32x4*)(hB + (hrr * 18 + hcc) * 128 + ((s * 16) ^ ((hcc & 7) << 4))) = v;
        }
        __syncthreads();

        int aoff[4];
#pragma unroll
        for (int m = 0; m < 4; ++m)
            aoff[m] = (m * 16 + cl) * 64 + ((q * 16) ^ ((cl & 3) << 4));

        const char* AsRd = (const char*)&As[0][0];
#pragma unroll
        for (int ks = 0; ks < 18; ++ks) {                  // ks' = kb*9+tap
            const int buf = ks & 1;
            if (ks < 17)
                gload_lds16(agp + (ks + 1) * 64, (char*)&As[buf ^ 1][0] + tid * 16);

            const int kb = ks / 9, tap = ks % 9;
            const int ky = tap / 3, kx = tap - ky * 3;

            u32x4 af[4];
#pragma unroll
            for (int m = 0; m < 4; ++m)
                af[m] = *(const u32x4*)(AsRd + buf * 4096 + aoff[m]);

            int hcv  = cl + kx;
            int cbase = hcv * 128 + ((kb * 64 + q * 16) ^ ((hcv & 7) << 4));
#pragma unroll
            for (int n = 0; n < N_; ++n) {
                int hr = wv * N_ + n + ky;
                u32x4 bv = *(const u32x4*)(hB + hr * 2304 + cbase);
                bf16x8 bfr = __builtin_bit_cast(bf16x8, bv);
#pragma unroll
                for (int m = 0; m < 4; ++m)
                    acc[m][n] = __builtin_amdgcn_mfma_f32_16x16x32_bf16(
                        __builtin_bit_cast(bf16x8, af[m]), bfr, acc[m][n], 0, 0, 0);
            }
            __syncthreads();                               // drains prefetch
        }
    }

    // ---- y[img][pix][r]: 8B packed store per (m,n) ----
#pragma unroll
    for (int m = 0; m < 4; ++m) {
#pragma unroll
        for (int n = 0; n < N_; ++n) {
            int pix = (py0 + wv * N_ + n) * 64 + px0 + cl;
            uint2 w;
            w.x = (unsigned)f2bf(acc[m][n][0]) | ((unsigned)f2bf(acc[m][n][1]) << 16);
            w.y = (unsigned)f2bf(acc[m][n][2]) | ((unsigned)f2bf(acc[m][n][3]) << 16);
            *(uint2*)(ybf + ((size_t)img * 4096 + pix) * 256 + rowbase + m * 16 + q * 4) = w;
        }
    }
    // ---- fused BN partial stats: per-block 64-channel (sum, sumsq) ----
    float* bnred = (float*)halo;         // 512 B reuse (k-loop reads done)
#pragma unroll
    for (int m = 0; m < 4; ++m) {
#pragma unroll
        for (int j = 0; j < 4; ++j) {
            float s = 0.f, qq = 0.f;
#pragma unroll
            for (int n = 0; n < N_; ++n) {
                float v = acc[m][n][j];
                s += v; qq += v * v;
            }
#pragma unroll
            for (int mask = 1; mask <= 8; mask <<= 1) {
                s  += __shfl_xor(s,  mask, 64);
                qq += __shfl_xor(qq, mask, 64);
            }
            if (cl == 0) {
                int ci_ = (wv * 4 + q) * 16 + m * 4 + j;
                bnred[ci_ * 2]     = s;
                bnred[ci_ * 2 + 1] = qq;
            }
        }
    }
    __syncthreads();
    if (tid < 64) {
        int m_ = tid >> 4, qj = tid & 15;      // local ch = m*16 + q*4 + j
        float s = 0.f, qq = 0.f;
#pragma unroll
        for (int w = 0; w < 4; ++w) {
            int idx = ((w * 4 + (qj >> 2)) * 16 + m_ * 4 + (qj & 3)) * 2;
            s += bnred[idx]; qq += bnred[idx + 1];
        }
        prt[(size_t)(rowbase + tid) * 1024 + img * 16 + tile] = make_float2(s, qq);
    }
}

// ---------------------------------------------------------------------------
// BN finalize: reduce 1024 per-block partials per channel r -> scale/shift.
// r = hc*4+g  ->  orig co = (r&3)*64 + (r>>2) for gamma/beta lookup.
// ---------------------------------------------------------------------------
__global__ __launch_bounds__(256) void k_bn_fin(
    const float2* __restrict__ prt, const float* __restrict__ bx,
    const float* __restrict__ gamma, const float* __restrict__ beta,
    float* __restrict__ ss) {
    int c = blockIdx.x;                       // 256 blocks (r-index)
    const float2* p = prt + (size_t)c * 1024;
    float s = 0.f, sq = 0.f;
    for (int i = threadIdx.x; i < 1024; i += 256) {
        float2 v = p[i]; s += v.x; sq += v.y;
    }
    __shared__ float rs[256], rq[256];
    int tid = threadIdx.x;
    rs[tid] = s; rq[tid] = sq;
    __syncthreads();
    for (int off = 128; off > 0; off >>= 1) {
        if (tid < off) { rs[tid] += rs[tid + off]; rq[tid] += rq[tid + off]; }
        __syncthreads();
    }
    if (tid == 0) {
        int co = (c & 3) * 64 + (c >> 2);
        float mean = rs[0] * (1.f / 262144.f);
        float var  = rq[0] * (1.f / 262144.f) - mean * mean;
        float sc   = gamma[co] * rsqrtf(var + 1e-5f);
        ss[c]       = sc;
        // conv bias bx cancels exactly in train-mode BN (mean contains it);
        // y was stored WITHOUT bias, so stats already match the bias-free conv:
        ss[256 + c] = beta[co] - mean * sc;
        (void)bx;
    }
}

// ---------------------------------------------------------------------------
// LSTM step (TH=8, N_=2, grid 512, full 8-slot halo).  kb-major K decode.
// y+c register prefetch; t=0 gates c to 0 (no cs memset needed).
// ---------------------------------------------------------------------------
__global__ __launch_bounds__(256) void k_step(
    const unsigned short* __restrict__ hin,   // h [4][4096][64] bf16 (t>0)
    const unsigned short* __restrict__ Ap,    // packed Wh (kb-major)
    const unsigned short* __restrict__ ybf,   // y [img64][pix][256r]
    const float* __restrict__ ss,             // [2][256] scale/shift
    float* __restrict__ cst,                  // c [4][64][4096] f32
    unsigned short* __restrict__ hout,        // h next [4][4096][64]
    float* __restrict__ out,                  // [16][4][64][4096]
    int t, int first)
{
    constexpr int TH = 8, N_ = 2, HR = 10;

    __shared__ __align__(16) unsigned short halo[HR * 18 * 64]; // 23040 B
    __shared__ __align__(16) unsigned short As[2][2048];        //  8192 B

    const int bid  = blockIdx.x;
    const int xcd  = bid & 7;
    const int sidx = bid >> 3;
    const int grp  = sidx & 3;
    const int pairG = (sidx >> 2) * 8 + xcd;  // 0..127
    const int tile = pairG & 31;
    const int img  = pairG >> 5;
    const int py0 = (tile >> 2) * TH, px0 = (tile & 3) * 16;
    const int tid = threadIdx.x;
    const int wv = tid >> 6, lane = tid & 63;
    const int cl = lane & 15, q = lane >> 4;
    const int rowbase = grp * 64;

    // ---- y + c prefetch (HBM latency hidden under k-loop) ----
    uint2 ypre[4][N_];
    float cpre[4][N_];
#pragma unroll
    for (int m = 0; m < 4; ++m) {
        int hc = grp * 16 + m * 4 + q;
#pragma unroll
        for (int n = 0; n < N_; ++n) {
            int pix = (py0 + wv * N_ + n) * 64 + px0 + cl;
            ypre[m][n] = *(const uint2*)(ybf +
                ((size_t)(t * 4 + img) * 4096 + pix) * 256 + hc * 4);
            cpre[m][n] = first ? 0.f : cst[((size_t)img * 64 + hc) * 4096 + pix];
        }
    }

    f32x4 acc[4][N_];
#pragma unroll
    for (int m = 0; m < 4; ++m)
#pragma unroll
        for (int n = 0; n < N_; ++n)
            acc[m][n] = (f32x4){0.f, 0.f, 0.f, 0.f};

    if (!first) {
        const char* agp = (const char*)Ap +
            (size_t)(rowbase + (tid >> 2)) * 1152 + (tid & 3) * 16;
        gload_lds16(agp, (char*)&As[0][0] + tid * 16);     // ks' = 0

        const unsigned short* sb = hin + (size_t)img * 4096 * 64;
        char* hB = (char*)halo;
        for (int tau = tid; tau < HR * 144; tau += 256) {
            int s = tau & 7, hcc = (tau >> 3) % 18, hrr = tau / 144;
            int gy = py0 + hrr - 1, gx = px0 + hcc - 1;
            u32x4 v = {0u, 0u, 0u, 0u};
            if ((unsigned)gy < 64u && (unsigned)gx < 64u)
                v = *(const u32x4*)(sb + ((gy * 64 + gx) * 64 + s * 8));
            *(u32x4*)(hB + (hrr * 18 + hcc) * 128 + ((s * 16) ^ ((hcc & 7) << 4))) = v;
        }
        __syncthreads();

        int aoff[4];
#pragma unroll
        for (int m = 0; m < 4; ++m)
            aoff[m] = (m * 16 + cl) * 64 + ((q * 16) ^ ((cl & 3) << 4));

        const char* AsRd = (const char*)&As[0][0];
#pragma unroll
        for (int ks = 0; ks < 18; ++ks) {                  // ks' = kb*9+tap
            const int buf = ks & 1;
            if (ks < 17)
                gload_lds16(agp + (ks + 1) * 64, (char*)&As[buf ^ 1][0] + tid * 16);

            const int kb = ks / 9, tap = ks % 9;
            const int ky = tap / 3, kx = tap - ky * 3;

            u32x4 af[4];
#pragma unroll
            for (int m = 0; m < 4; ++m)
                af[m] = *(const u32x4*)(AsRd + buf * 4096 + aoff[m]);

            int hcv  = cl + kx;
            int cbase = hcv * 128 + ((kb * 64 + q * 16) ^ ((hcv & 7) << 4));
#pragma unroll
            for (int n = 0; n < N_; ++n) {
                int hr = wv * N_ + n + ky;
                u32x4 bv = *(const u32x4*)(hB + hr * 2304 + cbase);
                bf16x8 bfr = __builtin_bit_cast(bf16x8, bv);
#pragma unroll
                for (int m = 0; m < 4; ++m)
                    acc[m][n] = __builtin_amdgcn_mfma_f32_16x16x32_bf16(
                        __builtin_bit_cast(bf16x8, af[m]), bfr, acc[m][n], 0, 0, 0);
            }
            __syncthreads();
        }
    }

    // ---- epilogue: gates, c, h ----
    unsigned short* hbounce = halo;          // reuse (k-loop reads done)
    const f32x4* sc4 = (const f32x4*)ss;
    const f32x4* sh4 = (const f32x4*)(ss + 256);
#pragma unroll
    for (int m = 0; m < 4; ++m) {
        int hc = grp * 16 + m * 4 + q;
        f32x4 sc = sc4[hc], sh = sh4[hc];
#pragma unroll
        for (int n = 0; n < N_; ++n) {
            int pix = (py0 + wv * N_ + n) * 64 + px0 + cl;
            uint2 yv = ypre[m][n];
            float tmp[4];
            tmp[0] = acc[m][n][0] + sc[0] * bf2f((unsigned short)(yv.x & 0xffffu)) + sh[0];
            tmp[1] = acc[m][n][1] + sc[1] * bf2f((unsigned short)(yv.x >> 16))     + sh[1];
            tmp[2] = acc[m][n][2] + sc[2] * bf2f((unsigned short)(yv.y & 0xffffu)) + sh[2];
            tmp[3] = acc[m][n][3] + sc[3] * bf2f((unsigned short)(yv.y >> 16))     + sh[3];
            float iv = 1.f / (1.f + __expf(-tmp[0]));
            float fv = 1.f / (1.f + __expf(-tmp[1]));
            float ov = 1.f / (1.f + __expf(-tmp[2]));
            float e2 = __expf(2.f * tmp[3]);
            float gv = 1.f - 2.f / (e2 + 1.f);
            size_t cidx = ((size_t)img * 64 + hc) * 4096 + pix;
            float cnew = fv * cpre[m][n] + iv * gv;
            cst[cidx] = cnew;
            float e2c = __expf(2.f * cnew);
            float hv  = ov * (1.f - 2.f / (e2c + 1.f));
            out[((size_t)(t * 4 + img) * 64 + hc) * 4096 + pix] = hv;
            hbounce[((wv * N_ + n) * 16 + cl) * 16 + m * 4 + q] = f2bf(hv);
        }
    }
    __syncthreads();
    // coalesced hT write-out: [img][pix][ci] slice grp*16..grp*16+15
    if (tid < TH * 16) {
        int pixg = (py0 + (tid >> 4)) * 64 + px0 + (tid & 15);
        u32x4* dst = (u32x4*)(hout + ((size_t)img * 4096 + pixg) * 64 + grp * 16);
        u32x4* s0  = (u32x4*)(hbounce + tid * 16);
        dst[0] = s0[0];
        dst[1] = s0[1];
    }
}

// ---------------------------------------------------------------------------
extern "C" void kernel_launch(void* const* d_in, const int* in_sizes, int n_in,
                              void* d_out, int out_size, void* d_ws, size_t ws_size,
                              hipStream_t stream) {
    const float* x     = (const float*)d_in[0];
    const float* Wx    = (const float*)d_in[1];
    const float* bx    = (const float*)d_in[2];
    const float* gamma = (const float*)d_in[3];
    const float* beta  = (const float*)d_in[4];
    const float* Wh    = (const float*)d_in[5];
    float* out = (float*)d_out;

    char* ws = (char*)d_ws;
    unsigned short* y   = (unsigned short*)ws;                  // 134,217,728
    unsigned short* Axp = (unsigned short*)(ws + 134217728);    //     294,912
    unsigned short* Ahp = (unsigned short*)(ws + 134512640);    //     294,912
    float*          ss  = (float*)(ws + 134807552);             //       2,048
    float*          cs  = (float*)(ws + 134809600);             //   4,194,304
    // prt and hA share a 2 MB slot: prt is produced by k_conv0 and fully
    // consumed by k_bn_fin before k_step first writes hA (at t=1).
    float2*         prt = (float2*)(ws + 139003904);            //   2,097,152
    unsigned short* hA  = (unsigned short*)(ws + 139003904);    //   (alias)
    unsigned short* hB  = (unsigned short*)(ws + 141101056);    //   2,097,152
    // total 143,198,208 B

    // xT scratch lives in d_out (dead once steps start overwriting it)
    unsigned short* xT = (unsigned short*)d_out;

    k_xT  <<<1024, 256, 0, stream>>>(x, xT);
    k_pack<<< 576, 256, 0, stream>>>(Wx, Axp);
    k_pack<<< 576, 256, 0, stream>>>(Wh, Ahp);

    k_conv0<<<4096, 256, 0, stream>>>(xT, Axp, y, prt);
    k_bn_fin<<<256, 256, 0, stream>>>(prt, bx, gamma, beta, ss);

    unsigned short* hbuf[2] = {hA, hB};
    for (int t = 0; t < 16; ++t) {
        k_step<<<512, 256, 0, stream>>>(hbuf[t & 1], Ahp, y, ss, cs,
                                        hbuf[(t + 1) & 1], out, t, t == 0 ? 1 : 0);
    }
}